// Round 24
// baseline (327.822 us; speedup 1.0000x reference)
//
#include <hip/hip_runtime.h>

#define NB 32
#define NPTS 1024
#define NP 256
#define NS 16
#define NC 256
#define NH 128
#define NOUT 97
#define RP 16   // LDS row stride (floats)
#define NT (NB * NP)   // 8192 tiles
#define NGF (NB * (NPTS / 16))   // 2048 gfeat tiles

// ---------------------------------------------------------------------------
// Prep. o2 layout for all main matrices: wl[(c*64+m)*2+t] = W[m+64t][c].
// ---------------------------------------------------------------------------
__global__ __launch_bounds__(256) void prep_kernel(
    const float* __restrict__ sa_w0, const float* __restrict__ sa_w1,
    const float* __restrict__ sa_w2, const float* __restrict__ fc_w1,
    const float* __restrict__ fc_w2, const float* __restrict__ fc_w3,
    float* __restrict__ w0l, float* __restrict__ w0x,
    float* __restrict__ wl1, float* __restrict__ wl2,
    float* __restrict__ fl1, float* __restrict__ fl2,
    float* __restrict__ fl3)
{
  int t = blockIdx.x * 256 + threadIdx.x;
  if (t >= 256 * 128) return;
  int c = t >> 7, o = t & 127;
  w0l[(c * 32 + (o & 31)) * 4 + (o >> 5)] = sa_w0[o * 259 + 3 + c];
  if (c < 3) w0x[c * 128 + o] = sa_w0[o * 259 + c];
  if (c < 128) {
    int qi = (c * 64 + (o & 63)) * 2 + (o >> 6);
    wl1[qi] = sa_w1[o * 128 + c];
    wl2[qi] = sa_w2[o * 128 + c];
    fl1[qi] = fc_w1[o * 128 + c];
    fl2[qi] = fc_w2[o * 128 + c];
    fl3[qi] = (o < NOUT) ? fc_w3[o * 128 + c] : 0.0f;
  }
}

// DPP fmax step (16-lane rows): row_shr:1/2/4/8, bcast15, bcast31
template <int CTRL>
__device__ __forceinline__ float dpp_fmax(float v) {
  float o = __int_as_float(
      __builtin_amdgcn_mov_dpp(__float_as_int(v), CTRL, 0xF, 0xF, true));
  return fmaxf(v, o);   // bound_ctrl: invalid lanes -> 0; v >= 0 so identity
}

// ---------------------------------------------------------------------------
// Fused 2-batch FPS + gfeat, launch_bounds(64,1): 256-VGPR budget so BOTH
// batches' coords+dist (~160 regs) stay register-resident (R19's failure was
// the default 8-wave/64-reg budget). Two serial chains interleave in one
// instruction stream: batch B's dist-update issues inside batch A's LDS-read
// and ladder stalls. Per-batch decision math is VERBATIM the R23-passing
// form (inline first-max chain + value DPP ladder + ballot + readlane).
//   blocks [0, NB/2):        FPS, two batches per wave.
//   blocks [NB/2, NB/2+NGF): gfeat, j-split-2 (R23-measured).
// ---------------------------------------------------------------------------
__global__ __launch_bounds__(64, 1) void fused_fps_gfeat_kernel(
    const float* __restrict__ xyz, int* __restrict__ inds,
    const float* __restrict__ features, const float* __restrict__ w0l,
    float* __restrict__ G)
{
  __shared__ __align__(16) float smem[NPTS * 6];   // 24 KB (fps2); gfeat: 16 KB
  const int lane = threadIdx.x;

  if (blockIdx.x < NB / 2) {
    // ------------------------- FPS x2 -------------------------
    const int b0 = blockIdx.x * 2;
    const float* xbA = xyz + (size_t)b0 * NPTS * 3;
    const float* xbB = xbA + NPTS * 3;
    float* sAx = smem;            float* sAy = smem + NPTS;     float* sAz = smem + 2 * NPTS;
    float* sBx = smem + 3 * NPTS; float* sBy = smem + 4 * NPTS; float* sBz = smem + 5 * NPTS;
    float pxA[16], pyA[16], pzA[16], dA[16];
    float pxB[16], pyB[16], pzB[16], dB[16];
    const float4* srcA = reinterpret_cast<const float4*>(xbA + lane * 48);
    const float4* srcB = reinterpret_cast<const float4*>(xbB + lane * 48);
#pragma unroll
    for (int q = 0; q < 4; ++q) {
      float4 a0 = srcA[3 * q], a1 = srcA[3 * q + 1], a2 = srcA[3 * q + 2];
      float4 c0 = srcB[3 * q], c1 = srcB[3 * q + 1], c2 = srcB[3 * q + 2];
      const float axv[4] = {a0.x, a0.w, a1.z, a2.y};
      const float ayv[4] = {a0.y, a1.x, a1.w, a2.z};
      const float azv[4] = {a0.z, a1.y, a2.x, a2.w};
      const float bxv[4] = {c0.x, c0.w, c1.z, c2.y};
      const float byv[4] = {c0.y, c1.x, c1.w, c2.z};
      const float bzv[4] = {c0.z, c1.y, c2.x, c2.w};
#pragma unroll
      for (int t = 0; t < 4; ++t) {
        int j = 4 * q + t;
        pxA[j] = axv[t]; pyA[j] = ayv[t]; pzA[j] = azv[t];
        pxB[j] = bxv[t]; pyB[j] = byv[t]; pzB[j] = bzv[t];
        sAx[lane * 16 + j] = axv[t];
        sAy[lane * 16 + j] = ayv[t];
        sAz[lane * 16 + j] = azv[t];
        sBx[lane * 16 + j] = bxv[t];
        sBy[lane * 16 + j] = byv[t];
        sBz[lane * 16 + j] = bzv[t];
      }
    }
#pragma unroll
    for (int j = 0; j < 16; ++j) { dA[j] = 1e10f; dB[j] = 1e10f; }
    int farA = 0, farB = 0;
    for (int i = 0; i < NP; ++i) {
      if (lane == 0) {
        inds[b0 * NP + i] = farA;
        inds[(b0 + 1) * NP + i] = farB;
      }
      float cxA = sAx[farA], cyA = sAy[farA], czA = sAz[farA];   // uniform
      float cxB = sBx[farB], cyB = sBy[farB], czB = sBz[farB];
      float bvA = -1.0f; int biA = 0;
      float bvB = -1.0f; int biB = 0;
#pragma unroll
      for (int j = 0; j < 16; ++j) {
#pragma clang fp contract(off)
        float dxA = pxA[j] - cxA, dyA = pyA[j] - cyA, dzA = pzA[j] - czA;
        float ddA = (dxA * dxA + dyA * dyA) + dzA * dzA;
        float ndA = fminf(dA[j], ddA);
        dA[j] = ndA;
        if (ndA > bvA) { bvA = ndA; biA = lane * 16 + j; }  // ascending: first max
        float dxB = pxB[j] - cxB, dyB = pyB[j] - cyB, dzB = pzB[j] - czB;
        float ddB = (dxB * dxB + dyB * dyB) + dzB * dzB;
        float ndB = fminf(dB[j], ddB);
        dB[j] = ndB;
        if (ndB > bvB) { bvB = ndB; biB = lane * 16 + j; }
      }
      // interleaved value ladders; lane 63 holds each wave max
      float rA = bvA, rB = bvB;
      rA = dpp_fmax<0x111>(rA); rB = dpp_fmax<0x111>(rB);
      rA = dpp_fmax<0x112>(rA); rB = dpp_fmax<0x112>(rB);
      rA = dpp_fmax<0x114>(rA); rB = dpp_fmax<0x114>(rB);
      rA = dpp_fmax<0x118>(rA); rB = dpp_fmax<0x118>(rB);
      rA = dpp_fmax<0x142>(rA); rB = dpp_fmax<0x142>(rB);
      rA = dpp_fmax<0x143>(rA); rB = dpp_fmax<0x143>(rB);
      float gmaxA = __int_as_float(__builtin_amdgcn_readlane(__float_as_int(rA), 63));
      float gmaxB = __int_as_float(__builtin_amdgcn_readlane(__float_as_int(rB), 63));
      // first-max index: lowest lane with bv==gmax (lanes index-ordered;
      // bi is that lane's first local max) -> exact first-max semantics
      unsigned long long mA = __ballot(bvA == gmaxA);
      unsigned long long mB = __ballot(bvB == gmaxB);
      int lA = __ffsll(mA) - 1;
      int lB = __ffsll(mB) - 1;
      farA = __builtin_amdgcn_readlane(biA, lA);
      farB = __builtin_amdgcn_readlane(biB, lB);
    }
    return;
  }

  // ------------------------- gfeat (j-split-2) -------------------------
  const int blk = blockIdx.x - NB / 2;
  const int b  = blk >> 6;
  const int n0 = (blk & 63) * 16;
  const int og = lane & 31;
  const int jg = lane >> 5;
  const int joff = jg * 8;
  const float* fb = features + b * NC * NPTS;
#pragma unroll
  for (int r = 0; r < 4; ++r) {
    int c = r * 64 + lane;
    const float4* s4 = reinterpret_cast<const float4*>(fb + c * NPTS + n0);
    float4 v0 = s4[0], v1 = s4[1], v2 = s4[2], v3 = s4[3];
    float* row = smem + c * RP;
    reinterpret_cast<float4*>(row)[0] = v0;
    reinterpret_cast<float4*>(row)[1] = v1;
    reinterpret_cast<float4*>(row)[2] = v2;
    reinterpret_cast<float4*>(row)[3] = v3;
  }
  float acc[4][8];
#pragma unroll
  for (int k = 0; k < 4; ++k)
#pragma unroll
    for (int nn = 0; nn < 8; ++nn) acc[k][nn] = 0.0f;
#pragma unroll 2
  for (int c = 0; c < NC; ++c) {
    const float4 wq = *reinterpret_cast<const float4*>(w0l + (c * 32 + og) * 4);
    const float* row = smem + c * RP + joff;
    const float4 xa = reinterpret_cast<const float4*>(row)[0];
    const float4 xb4 = reinterpret_cast<const float4*>(row)[1];
    const float wk[4] = {wq.x, wq.y, wq.z, wq.w};
    const float xr[8] = {xa.x, xa.y, xa.z, xa.w, xb4.x, xb4.y, xb4.z, xb4.w};
#pragma unroll
    for (int k = 0; k < 4; ++k)
#pragma unroll
      for (int nn = 0; nn < 8; ++nn)
        acc[k][nn] = fmaf(wk[k], xr[nn], acc[k][nn]);
  }
#pragma unroll
  for (int k = 0; k < 4; ++k) {
    int o = og + 32 * k;
    float* gp = G + ((size_t)(b * NPTS + n0 + joff)) * NH + o;
#pragma unroll
    for (int nn = 0; nn < 8; ++nn) gp[nn * NH] = acc[k][nn];
  }
}

// ---------------------------------------------------------------------------
// Ball query (bit-identical decision math). NO atomics: writes totals only.
// ---------------------------------------------------------------------------
__global__ __launch_bounds__(256) void ball_kernel(
    const float* __restrict__ xyz, const int* __restrict__ inds,
    int* __restrict__ nbr, float* __restrict__ gx, int* __restrict__ totals)
{
  const int wid  = blockIdx.x * 4 + (threadIdx.x >> 6);   // == b*NP + p
  const int lane = threadIdx.x & 63;
  const int b = wid >> 8;
  const float* xb = xyz + b * NPTS * 3;
  const int ci = inds[wid];
  const float cx = xb[ci * 3 + 0], cy = xb[ci * 3 + 1], cz = xb[ci * 3 + 2];
  float nq;
  {
#pragma clang fp contract(off)
    nq = (cx * cx + cy * cy) + cz * cz;
  }
  const float R2 = 0.09f;
  unsigned mask = 0;
  int cntj = 0, firstn = NPTS;
  for (int j = 0; j < 16; ++j) {
#pragma clang fp contract(off)
    int n = lane * 16 + j;   // lane-major: global order == lexicographic
    float x = xb[n * 3 + 0], y = xb[n * 3 + 1], z = xb[n * 3 + 2];
    float nx = (x * x + y * y) + z * z;
    float dt = (cx * x + cy * y) + cz * z;
    float d2 = (nq + nx) - 2.0f * dt;
    if (d2 < R2) { mask |= 1u << j; ++cntj; if (firstn == NPTS) firstn = n; }
  }
  int inc = cntj;
  for (int off = 1; off < 64; off <<= 1) {
    int v = __shfl_up(inc, off);
    if (lane >= off) inc += v;
  }
  int rank  = inc - cntj;
  int total = __shfl(inc, 63);
  for (int j = 0; j < 16; ++j) {
    if (mask & (1u << j)) {
      if (rank < NS) {
        int n = lane * 16 + j;
        nbr[wid * NS + rank] = n;
        float x = xb[n * 3 + 0], y = xb[n * 3 + 1], z = xb[n * 3 + 2];
        gx[wid * 48 + rank * 3 + 0] = (x - cx) / 0.3f;
        gx[wid * 48 + rank * 3 + 1] = (y - cy) / 0.3f;
        gx[wid * 48 + rank * 3 + 2] = (z - cz) / 0.3f;
      }
      ++rank;
    }
  }
  int fmin = firstn;
  for (int off2 = 32; off2 > 0; off2 >>= 1) {
    int ov = __shfl_xor(fmin, off2);
    fmin = min(fmin, ov);
  }
  if (lane < NS && lane >= total) {
    nbr[wid * NS + lane] = fmin;
    float x = xb[fmin * 3 + 0], y = xb[fmin * 3 + 1], z = xb[fmin * 3 + 2];
    gx[wid * 48 + lane * 3 + 0] = (x - cx) / 0.3f;
    gx[wid * 48 + lane * 3 + 1] = (y - cy) / 0.3f;
    gx[wid * 48 + lane * 3 + 2] = (z - cz) / 0.3f;
  }
  if (lane == 0) totals[wid] = total;
}

// ---------------------------------------------------------------------------
// Deterministic bucket build: one block, 1024 threads, 8 tiles each.
// FOUR J-classes: <=2 (pack8), <=4 (pack4), <=8 (pack2), else (pack1).
// Packed-u64 scan (4 class counts x 16 bits). Stable within class.
// ---------------------------------------------------------------------------
__global__ __launch_bounds__(1024) void scan_kernel(
    const int* __restrict__ totals, int* __restrict__ bucket, int* __restrict__ cnt)
{
  __shared__ unsigned long long ssum[16];
  const int t = threadIdx.x;
  int cls[8];
  unsigned long long local = 0;
#pragma unroll
  for (int k = 0; k < 8; ++k) {
    int tot = totals[t * 8 + k];
    int jc = (tot <= 2) ? 0 : (tot <= 4) ? 1 : (tot <= 8) ? 2 : 3;
    cls[k] = jc;
    local += 1ull << (jc * 16);
  }
  unsigned long long inc = local;
  for (int off = 1; off < 64; off <<= 1) {
    unsigned long long v = __shfl_up(inc, off);
    if ((t & 63) >= off) inc += v;
  }
  if ((t & 63) == 63) ssum[t >> 6] = inc;
  __syncthreads();
  if (t == 0) {
    unsigned long long run = 0;
    for (int i = 0; i < 16; ++i) { unsigned long long v = ssum[i]; ssum[i] = run; run += v; }
    cnt[0] = (int)(run & 0xFFFFull);
    cnt[1] = (int)((run >> 16) & 0xFFFFull);
    cnt[2] = (int)((run >> 32) & 0xFFFFull);
    cnt[3] = (int)((run >> 48) & 0xFFFFull);
  }
  __syncthreads();
  unsigned long long excl = (inc - local) + ssum[t >> 6];
  int p0 = (int)(excl & 0xFFFFull);
  int p1 = (int)((excl >> 16) & 0xFFFFull);
  int p2 = (int)((excl >> 32) & 0xFFFFull);
  int p3 = (int)((excl >> 48) & 0xFFFFull);
#pragma unroll
  for (int k = 0; k < 8; ++k) {
    int id = t * 8 + k;
    if (cls[k] == 0)      { bucket[p0] = id; ++p0; }
    else if (cls[k] == 1) { bucket[NT + p1] = id; ++p1; }
    else if (cls[k] == 2) { bucket[2 * NT + p2] = id; ++p2; }
    else                  { bucket[3 * NT + p3] = id; ++p3; }
  }
}

// ---------------------------------------------------------------------------
// 16-slot MLP core (L0 -> L1 -> L2), o2 scheme: lane owns o in {lane,lane+64},
// all 16 slots in registers. acc left raw (pre-BN) for per-tile maxpool.
// ---------------------------------------------------------------------------
__device__ __forceinline__ void mlp16(
    float* __restrict__ xs, const int lane,
    const float* __restrict__ G, const int* __restrict__ idxw,
    const float* __restrict__ gxw,
    const float* __restrict__ w0x, const float* __restrict__ s0v, const float* __restrict__ t0v,
    const float* __restrict__ wl1, const float* __restrict__ s1v, const float* __restrict__ t1v,
    const float* __restrict__ wl2,
    float acc0[16], float acc1[16])
{
  // ---- L0 ----
  {
    const float wa0 = w0x[lane],      wb0 = w0x[128 + lane],      wc0 = w0x[256 + lane];
    const float wa1 = w0x[64 + lane], wb1 = w0x[192 + lane],      wc1 = w0x[320 + lane];
    const float ss0 = s0v[lane], tt0 = t0v[lane];
    const float ss1 = s0v[64 + lane], tt1 = t0v[64 + lane];
    float r0[16], r1[16];
#pragma unroll
    for (int j = 0; j < 16; ++j) {
      int gj = idxw[j];                       // prefolded b*NPTS + nbr
      float gxv = gxw[j * 3 + 0], gyv = gxw[j * 3 + 1], gzv = gxw[j * 3 + 2];
      const float* gp = G + (size_t)gj * NH;
      float g0 = gp[lane], g1 = gp[lane + 64];
      float y0 = fmaf(wa0, gxv, fmaf(wb0, gyv, fmaf(wc0, gzv, g0)));
      float y1 = fmaf(wa1, gxv, fmaf(wb1, gyv, fmaf(wc1, gzv, g1)));
      r0[j] = fmaxf(fmaf(y0, ss0, tt0), 0.0f);
      r1[j] = fmaxf(fmaf(y1, ss1, tt1), 0.0f);
    }
#pragma unroll
    for (int q = 0; q < 4; ++q) {
      *reinterpret_cast<float4*>(xs + lane * RP + q * 4) =
          make_float4(r0[4 * q], r0[4 * q + 1], r0[4 * q + 2], r0[4 * q + 3]);
      *reinterpret_cast<float4*>(xs + (lane + 64) * RP + q * 4) =
          make_float4(r1[4 * q], r1[4 * q + 1], r1[4 * q + 2], r1[4 * q + 3]);
    }
  }

  // ---- L1 ----
#pragma unroll
  for (int j = 0; j < 16; ++j) { acc0[j] = 0.0f; acc1[j] = 0.0f; }
#pragma unroll 2
  for (int c = 0; c < NH; ++c) {
    const float2 wv = *reinterpret_cast<const float2*>(wl1 + (c * 64 + lane) * 2);
#pragma unroll
    for (int q = 0; q < 4; ++q) {
      const float4 xq = *reinterpret_cast<const float4*>(xs + c * RP + q * 4);
      acc0[4 * q + 0] = fmaf(wv.x, xq.x, acc0[4 * q + 0]);
      acc1[4 * q + 0] = fmaf(wv.y, xq.x, acc1[4 * q + 0]);
      acc0[4 * q + 1] = fmaf(wv.x, xq.y, acc0[4 * q + 1]);
      acc1[4 * q + 1] = fmaf(wv.y, xq.y, acc1[4 * q + 1]);
      acc0[4 * q + 2] = fmaf(wv.x, xq.z, acc0[4 * q + 2]);
      acc1[4 * q + 2] = fmaf(wv.y, xq.z, acc1[4 * q + 2]);
      acc0[4 * q + 3] = fmaf(wv.x, xq.w, acc0[4 * q + 3]);
      acc1[4 * q + 3] = fmaf(wv.y, xq.w, acc1[4 * q + 3]);
    }
  }
  // BN+ReLU, write x2 (in-wave LDS ordering: own-plane reads precede writes)
  {
    const float ssa = s1v[lane], tta = t1v[lane];
    const float ssb = s1v[64 + lane], ttb = t1v[64 + lane];
#pragma unroll
    for (int q = 0; q < 4; ++q) {
      float4 ra, rb;
      ra.x = fmaxf(fmaf(acc0[4 * q + 0], ssa, tta), 0.0f);
      ra.y = fmaxf(fmaf(acc0[4 * q + 1], ssa, tta), 0.0f);
      ra.z = fmaxf(fmaf(acc0[4 * q + 2], ssa, tta), 0.0f);
      ra.w = fmaxf(fmaf(acc0[4 * q + 3], ssa, tta), 0.0f);
      rb.x = fmaxf(fmaf(acc1[4 * q + 0], ssb, ttb), 0.0f);
      rb.y = fmaxf(fmaf(acc1[4 * q + 1], ssb, ttb), 0.0f);
      rb.z = fmaxf(fmaf(acc1[4 * q + 2], ssb, ttb), 0.0f);
      rb.w = fmaxf(fmaf(acc1[4 * q + 3], ssb, ttb), 0.0f);
      *reinterpret_cast<float4*>(xs + lane * RP + q * 4) = ra;
      *reinterpret_cast<float4*>(xs + (lane + 64) * RP + q * 4) = rb;
    }
  }

  // ---- L2 (raw acc; BN+maxpool done by caller per tile) ----
#pragma unroll
  for (int j = 0; j < 16; ++j) { acc0[j] = 0.0f; acc1[j] = 0.0f; }
#pragma unroll 2
  for (int c = 0; c < NH; ++c) {
    const float2 wv = *reinterpret_cast<const float2*>(wl2 + (c * 64 + lane) * 2);
#pragma unroll
    for (int q = 0; q < 4; ++q) {
      const float4 xq = *reinterpret_cast<const float4*>(xs + c * RP + q * 4);
      acc0[4 * q + 0] = fmaf(wv.x, xq.x, acc0[4 * q + 0]);
      acc1[4 * q + 0] = fmaf(wv.y, xq.x, acc1[4 * q + 0]);
      acc0[4 * q + 1] = fmaf(wv.x, xq.y, acc0[4 * q + 1]);
      acc1[4 * q + 1] = fmaf(wv.y, xq.y, acc1[4 * q + 1]);
      acc0[4 * q + 2] = fmaf(wv.x, xq.z, acc0[4 * q + 2]);
      acc1[4 * q + 2] = fmaf(wv.y, xq.z, acc1[4 * q + 2]);
      acc0[4 * q + 3] = fmaf(wv.x, xq.w, acc0[4 * q + 3]);
      acc1[4 * q + 3] = fmaf(wv.y, xq.w, acc1[4 * q + 3]);
    }
  }
}

// ---------------------------------------------------------------------------
// Epilogue for TPW tiles (16/TPW slots each): maxpool per tile -> FC1/2/3.
// Tile ids come from LDS (tl[k], compile-time k). f at xs[k*128..],
// h at xs[TPW*128 + k*128..]. TPW=8 uses exactly the 2048-float plane.
// ---------------------------------------------------------------------------
template <int TPW>
__device__ __forceinline__ void fc_epilogue(
    float* __restrict__ xs, const int lane, const int* __restrict__ tl,
    float acc0[16], float acc1[16],
    const float* __restrict__ s2v, const float* __restrict__ t2v,
    const float* __restrict__ fl1, const float* __restrict__ fs1, const float* __restrict__ ft1,
    const float* __restrict__ fl2, const float* __restrict__ fs2, const float* __restrict__ ft2,
    const float* __restrict__ fl3, const float* __restrict__ b3, float* __restrict__ out)
{
  constexpr int SPT = 16 / TPW;
  // ---- per-tile BN+ReLU+maxpool -> f vectors ----
  {
    const float ssa = s2v[lane], tta = t2v[lane];
    const float ssb = s2v[64 + lane], ttb = t2v[64 + lane];
#pragma unroll
    for (int k = 0; k < TPW; ++k) {
      float fo0 = 0.0f, fo1 = 0.0f;
#pragma unroll
      for (int r = 0; r < SPT; ++r) {
        fo0 = fmaxf(fo0, fmaxf(fmaf(acc0[k * SPT + r], ssa, tta), 0.0f));
        fo1 = fmaxf(fo1, fmaxf(fmaf(acc1[k * SPT + r], ssb, ttb), 0.0f));
      }
      xs[k * 128 + lane] = fo0;
      xs[k * 128 + 64 + lane] = fo1;
    }
  }
  constexpr int HB = TPW * 128;

  float h0[TPW], h1[TPW];

  // ---- FC1 ----
#pragma unroll
  for (int k = 0; k < TPW; ++k) { h0[k] = 0.0f; h1[k] = 0.0f; }
#pragma unroll 4
  for (int c4 = 0; c4 < 32; ++c4) {
    float4 fq[TPW];
#pragma unroll
    for (int k = 0; k < TPW; ++k)
      fq[k] = *reinterpret_cast<const float4*>(xs + k * 128 + c4 * 4);
#pragma unroll
    for (int cc = 0; cc < 4; ++cc) {
      const float2 wv = *reinterpret_cast<const float2*>(fl1 + ((c4 * 4 + cc) * 64 + lane) * 2);
#pragma unroll
      for (int k = 0; k < TPW; ++k) {
        float fv = (cc == 0) ? fq[k].x : (cc == 1) ? fq[k].y : (cc == 2) ? fq[k].z : fq[k].w;
        h0[k] = fmaf(wv.x, fv, h0[k]);
        h1[k] = fmaf(wv.y, fv, h1[k]);
      }
    }
  }
#pragma unroll
  for (int k = 0; k < TPW; ++k) {
    xs[HB + k * 128 + lane]      = fmaxf(fmaf(h0[k], fs1[lane],      ft1[lane]),      0.0f);
    xs[HB + k * 128 + 64 + lane] = fmaxf(fmaf(h1[k], fs1[lane + 64], ft1[lane + 64]), 0.0f);
  }

  // ---- FC2 ----
#pragma unroll
  for (int k = 0; k < TPW; ++k) { h0[k] = 0.0f; h1[k] = 0.0f; }
#pragma unroll 4
  for (int c4 = 0; c4 < 32; ++c4) {
    float4 fq[TPW];
#pragma unroll
    for (int k = 0; k < TPW; ++k)
      fq[k] = *reinterpret_cast<const float4*>(xs + HB + k * 128 + c4 * 4);
#pragma unroll
    for (int cc = 0; cc < 4; ++cc) {
      const float2 wv = *reinterpret_cast<const float2*>(fl2 + ((c4 * 4 + cc) * 64 + lane) * 2);
#pragma unroll
      for (int k = 0; k < TPW; ++k) {
        float fv = (cc == 0) ? fq[k].x : (cc == 1) ? fq[k].y : (cc == 2) ? fq[k].z : fq[k].w;
        h0[k] = fmaf(wv.x, fv, h0[k]);
        h1[k] = fmaf(wv.y, fv, h1[k]);
      }
    }
  }
#pragma unroll
  for (int k = 0; k < TPW; ++k) {
    xs[k * 128 + lane]      = fmaxf(fmaf(h0[k], fs2[lane],      ft2[lane]),      0.0f);
    xs[k * 128 + 64 + lane] = fmaxf(fmaf(h1[k], fs2[lane + 64], ft2[lane + 64]), 0.0f);
  }

  // ---- FC3 ----
#pragma unroll
  for (int k = 0; k < TPW; ++k) { h0[k] = 0.0f; h1[k] = 0.0f; }
#pragma unroll 4
  for (int c4 = 0; c4 < 32; ++c4) {
    float4 fq[TPW];
#pragma unroll
    for (int k = 0; k < TPW; ++k)
      fq[k] = *reinterpret_cast<const float4*>(xs + k * 128 + c4 * 4);
#pragma unroll
    for (int cc = 0; cc < 4; ++cc) {
      const float2 wv = *reinterpret_cast<const float2*>(fl3 + ((c4 * 4 + cc) * 64 + lane) * 2);
#pragma unroll
      for (int k = 0; k < TPW; ++k) {
        float fv = (cc == 0) ? fq[k].x : (cc == 1) ? fq[k].y : (cc == 2) ? fq[k].z : fq[k].w;
        h0[k] = fmaf(wv.x, fv, h0[k]);
        h1[k] = fmaf(wv.y, fv, h1[k]);
      }
    }
  }
#pragma unroll
  for (int k = 0; k < TPW; ++k) {
    int tk = tl[k];                         // LDS read, compile-time k
    int b = tk >> 8, p = tk & 255;
    out[(b * NOUT + lane) * NP + p] = h0[k] + b3[lane];   // lane < 97 always
    if (lane < NOUT - 64)
      out[(b * NOUT + lane + 64) * NP + p] = h1[k] + b3[lane + 64];
  }
}

// ---------------------------------------------------------------------------
// Main kernel: 512-thread blocks = 8 independent waves (no barriers). Each
// wave carries a 16-slot task: 8xJ2, 4xJ4, 2xJ8, or 1xJ16 tiles via the
// class buckets. Tile ids routed through LDS (rule #20).
// ---------------------------------------------------------------------------
__global__ __launch_bounds__(512) void main_kernel(
    const int* __restrict__ nbr, const float* __restrict__ gx,
    const int* __restrict__ bucket, const int* __restrict__ cnt,
    const float* __restrict__ G,
    const float* __restrict__ w0x, const float* __restrict__ s0v, const float* __restrict__ t0v,
    const float* __restrict__ wl1, const float* __restrict__ s1v, const float* __restrict__ t1v,
    const float* __restrict__ wl2, const float* __restrict__ s2v, const float* __restrict__ t2v,
    const float* __restrict__ fl1, const float* __restrict__ fs1, const float* __restrict__ ft1,
    const float* __restrict__ fl2, const float* __restrict__ fs2, const float* __restrict__ ft2,
    const float* __restrict__ fl3, const float* __restrict__ b3, float* __restrict__ out)
{
  __shared__ __align__(16) float xt[8][NH * RP];   // 64 KB (8 waves)
  __shared__ float gxs[8][NS][3];
  __shared__ int   idxs[8][NS];
  __shared__ int   sh_t[8][8];

  const int w    = threadIdx.x >> 6;              // 0..7
  const int lane = threadIdx.x & 63;
  const int g    = blockIdx.x * 8 + w;

  const int c0 = cnt[0], c1 = cnt[1], c2 = cnt[2], c3 = cnt[3];
  const int n8 = (c0 + 7) >> 3;
  const int n4 = (c1 + 3) >> 2;
  const int n2 = (c2 + 1) >> 1;
  if (g >= n8 + n4 + n2 + c3) return;             // no barriers: early exit ok

  // wave-uniform pack class; each lane loads its own tile id (no reg arrays)
  int tpw, myt;
  if (g < n8) {
    tpw = 8;
    myt = bucket[min(8 * g + (lane & 7), c0 - 1)];
  } else if (g < n8 + n4) {
    tpw = 4;
    myt = bucket[NT + min(4 * (g - n8) + (lane & 3), c1 - 1)];
  } else if (g < n8 + n4 + n2) {
    tpw = 2;
    myt = bucket[2 * NT + min(2 * (g - n8 - n4) + (lane & 1), c2 - 1)];
  } else {
    tpw = 1;
    myt = bucket[3 * NT + (g - n8 - n4 - n2)];
  }
  if (lane < 8) sh_t[w][lane] = myt;

  float* xs = &xt[w][0];

  // ---- prologue: gather 16 (tile, slot) pairs into LDS ----
  if (lane < 16) {
    int ti, r;
    if (tpw == 8)      { ti = lane >> 1; r = lane & 1; }
    else if (tpw == 4) { ti = lane >> 2; r = lane & 3; }
    else if (tpw == 2) { ti = lane >> 3; r = lane & 7; }
    else               { ti = 0;         r = lane; }
    int tk = sh_t[w][ti];                 // LDS-indexed read (in-wave ordered)
    int bk = tk >> 8;
    idxs[w][lane] = bk * NPTS + nbr[tk * NS + r];
    gxs[w][lane][0] = gx[tk * 48 + r * 3 + 0];
    gxs[w][lane][1] = gx[tk * 48 + r * 3 + 1];
    gxs[w][lane][2] = gx[tk * 48 + r * 3 + 2];
  }
  // single wave owns its LDS plane: in-wave lgkmcnt orders write->read

  float acc0[16], acc1[16];
  mlp16(xs, lane, G, idxs[w], &gxs[w][0][0],
        w0x, s0v, t0v, wl1, s1v, t1v, wl2, acc0, acc1);

  if (tpw == 8) {
    fc_epilogue<8>(xs, lane, sh_t[w], acc0, acc1, s2v, t2v,
                   fl1, fs1, ft1, fl2, fs2, ft2, fl3, b3, out);
  } else if (tpw == 4) {
    fc_epilogue<4>(xs, lane, sh_t[w], acc0, acc1, s2v, t2v,
                   fl1, fs1, ft1, fl2, fs2, ft2, fl3, b3, out);
  } else if (tpw == 2) {
    fc_epilogue<2>(xs, lane, sh_t[w], acc0, acc1, s2v, t2v,
                   fl1, fs1, ft1, fl2, fs2, ft2, fl3, b3, out);
  } else {
    fc_epilogue<1>(xs, lane, sh_t[w], acc0, acc1, s2v, t2v,
                   fl1, fs1, ft1, fl2, fs2, ft2, fl3, b3, out);
  }
}

extern "C" void kernel_launch(void* const* d_in, const int* in_sizes, int n_in,
                              void* d_out, int out_size, void* d_ws, size_t ws_size,
                              hipStream_t stream) {
  const float* xyz      = (const float*)d_in[0];
  const float* features = (const float*)d_in[1];
  const float* sa_w0 = (const float*)d_in[2];
  const float* sa_s0 = (const float*)d_in[3];
  const float* sa_t0 = (const float*)d_in[4];
  const float* sa_w1 = (const float*)d_in[5];
  const float* sa_s1 = (const float*)d_in[6];
  const float* sa_t1 = (const float*)d_in[7];
  const float* sa_w2 = (const float*)d_in[8];
  const float* sa_s2 = (const float*)d_in[9];
  const float* sa_t2 = (const float*)d_in[10];
  const float* fc_w1 = (const float*)d_in[11];
  const float* fc_s1 = (const float*)d_in[12];
  const float* fc_t1 = (const float*)d_in[13];
  const float* fc_w2 = (const float*)d_in[14];
  const float* fc_s2 = (const float*)d_in[15];
  const float* fc_t2 = (const float*)d_in[16];
  const float* fc_w3 = (const float*)d_in[17];
  const float* fc_b3 = (const float*)d_in[18];
  float* out = (float*)d_out;

  char* ws = (char*)d_ws;
  int* inds = (int*)ws;            ws += (size_t)NT * sizeof(int);
  float* w0l  = (float*)ws;        ws += (size_t)256 * 128 * sizeof(float);
  float* w0x  = (float*)ws;        ws += (size_t)3 * 128 * sizeof(float);
  float* wl1  = (float*)ws;        ws += (size_t)128 * 128 * sizeof(float);
  float* wl2  = (float*)ws;        ws += (size_t)128 * 128 * sizeof(float);
  float* fl1  = (float*)ws;        ws += (size_t)128 * 128 * sizeof(float);
  float* fl2  = (float*)ws;        ws += (size_t)128 * 128 * sizeof(float);
  float* fl3  = (float*)ws;        ws += (size_t)128 * 128 * sizeof(float);
  float* G    = (float*)ws;        ws += (size_t)NB * NPTS * NH * sizeof(float);
  int*   nbr  = (int*)ws;          ws += (size_t)NT * NS * sizeof(int);
  float* gx   = (float*)ws;        ws += (size_t)NT * 48 * sizeof(float);
  int* totals = (int*)ws;          ws += (size_t)NT * sizeof(int);
  int* bucket = (int*)ws;          ws += (size_t)4 * NT * sizeof(int);
  int* cnt    = (int*)ws;          ws += 16 * sizeof(int);

  prep_kernel<<<128, 256, 0, stream>>>(sa_w0, sa_w1, sa_w2, fc_w1, fc_w2, fc_w3,
                                       w0l, w0x, wl1, wl2, fl1, fl2, fl3);
  fused_fps_gfeat_kernel<<<NB / 2 + NGF, 64, 0, stream>>>(
      xyz, inds, features, w0l, G);
  ball_kernel<<<NT / 4, 256, 0, stream>>>(xyz, inds, nbr, gx, totals);
  scan_kernel<<<1, 1024, 0, stream>>>(totals, bucket, cnt);
  main_kernel<<<NT / 8, 512, 0, stream>>>(
      nbr, gx, bucket, cnt, G,
      w0x, sa_s0, sa_t0,
      wl1, sa_s1, sa_t1,
      wl2, sa_s2, sa_t2,
      fl1, fc_s1, fc_t1,
      fl2, fc_s2, fc_t2,
      fl3, fc_b3, out);
}

// Round 25
// 234.173 us; speedup vs baseline: 1.3999x; 1.3999x over previous
//
#include <hip/hip_runtime.h>

#define NB 32
#define NPTS 1024
#define NP 256
#define NS 16
#define NC 256
#define NH 128
#define NOUT 97
#define RP 16   // LDS row stride (floats)
#define NT (NB * NP)   // 8192 tiles
#define NGF (NB * (NPTS / 16))   // 2048 gfeat tiles

// ---------------------------------------------------------------------------
// Prep. o2 layout for all main matrices: wl[(c*64+m)*2+t] = W[m+64t][c].
// ---------------------------------------------------------------------------
__global__ __launch_bounds__(256) void prep_kernel(
    const float* __restrict__ sa_w0, const float* __restrict__ sa_w1,
    const float* __restrict__ sa_w2, const float* __restrict__ fc_w1,
    const float* __restrict__ fc_w2, const float* __restrict__ fc_w3,
    float* __restrict__ w0l, float* __restrict__ w0x,
    float* __restrict__ wl1, float* __restrict__ wl2,
    float* __restrict__ fl1, float* __restrict__ fl2,
    float* __restrict__ fl3)
{
  int t = blockIdx.x * 256 + threadIdx.x;
  if (t >= 256 * 128) return;
  int c = t >> 7, o = t & 127;
  w0l[(c * 32 + (o & 31)) * 4 + (o >> 5)] = sa_w0[o * 259 + 3 + c];
  if (c < 3) w0x[c * 128 + o] = sa_w0[o * 259 + c];
  if (c < 128) {
    int qi = (c * 64 + (o & 63)) * 2 + (o >> 6);
    wl1[qi] = sa_w1[o * 128 + c];
    wl2[qi] = sa_w2[o * 128 + c];
    fl1[qi] = fc_w1[o * 128 + c];
    fl2[qi] = fc_w2[o * 128 + c];
    fl3[qi] = (o < NOUT) ? fc_w3[o * 128 + c] : 0.0f;
  }
}

// DPP reduction ladder steps (16-lane rows): row_shr:1/2/4/8, bcast15, bcast31
template <int CTRL>
__device__ __forceinline__ float dpp_fmax(float v) {
  float o = __int_as_float(
      __builtin_amdgcn_mov_dpp(__float_as_int(v), CTRL, 0xF, 0xF, true));
  return fmaxf(v, o);   // bound_ctrl: invalid lanes -> 0; v >= 0 so identity
}

// ---------------------------------------------------------------------------
// Fused FPS + gfeat (R23-measured: 134 us). FPS: value DPP ladder + ballot
// first-max (lanes index-ordered; each lane's bi is its first local max, so
// the lowest qualifying lane holds the globally-first index) + packed float4
// centroid mirror (one ds_read_b128 per lookup).
//   blocks [0, NB):       FPS, one wave per batch.
//   blocks [NB, NB+NGF):  gfeat, j-split-2.
// ---------------------------------------------------------------------------
__global__ __launch_bounds__(64) void fused_fps_gfeat_kernel(
    const float* __restrict__ xyz, int* __restrict__ inds,
    const float* __restrict__ features, const float* __restrict__ w0l,
    float* __restrict__ G)
{
  __shared__ __align__(16) float smem[NC * RP];   // 16 KB (= 1024 float4)
  const int lane = threadIdx.x;

  if (blockIdx.x < NB) {
    // ------------------------- FPS -------------------------
    const int b = blockIdx.x;
    const float* xb = xyz + b * NPTS * 3;
    float px[16], py[16], pz[16], dist[16];
    const float4* src = reinterpret_cast<const float4*>(xb + lane * 48);
#pragma unroll
    for (int q = 0; q < 4; ++q) {
      float4 v0 = src[3 * q], v1 = src[3 * q + 1], v2 = src[3 * q + 2];
      const float xv[4] = {v0.x, v0.w, v1.z, v2.y};
      const float yv[4] = {v0.y, v1.x, v1.w, v2.z};
      const float zv[4] = {v0.z, v1.y, v2.x, v2.w};
#pragma unroll
      for (int t = 0; t < 4; ++t) {
        int j = 4 * q + t;
        px[j] = xv[t]; py[j] = yv[t]; pz[j] = zv[t];
        // packed centroid mirror: one b128 read per lookup
        *reinterpret_cast<float4*>(smem + (lane * 16 + j) * 4) =
            make_float4(xv[t], yv[t], zv[t], 0.0f);
      }
    }
#pragma unroll
    for (int j = 0; j < 16; ++j) dist[j] = 1e10f;
    int far = 0;
    for (int i = 0; i < NP; ++i) {
      if (lane == 0) inds[b * NP + i] = far;
      const float4 cp = *reinterpret_cast<const float4*>(smem + far * 4);
      float cx = cp.x, cy = cp.y, cz = cp.z;   // uniform broadcast
      float bv = -1.0f; int bi = 0;
#pragma unroll
      for (int j = 0; j < 16; ++j) {
#pragma clang fp contract(off)
        float dx = px[j] - cx;
        float dy = py[j] - cy;
        float dz = pz[j] - cz;
        float d = (dx * dx + dy * dy) + dz * dz;
        float nd = fminf(dist[j], d);
        dist[j] = nd;
        if (nd > bv) { bv = nd; bi = lane * 16 + j; }   // ascending j: first max
      }
      // global max of bv (pure VALU DPP ladder), lane 63 holds result
      float r = bv;
      r = dpp_fmax<0x111>(r);   // row_shr:1
      r = dpp_fmax<0x112>(r);   // row_shr:2
      r = dpp_fmax<0x114>(r);   // row_shr:4
      r = dpp_fmax<0x118>(r);   // row_shr:8
      r = dpp_fmax<0x142>(r);   // row_bcast:15
      r = dpp_fmax<0x143>(r);   // row_bcast:31
      float gmax = __int_as_float(__builtin_amdgcn_readlane(__float_as_int(r), 63));
      // first-max index: lowest lane with bv==gmax holds the globally-first
      // index (lanes are index-ordered; bi is that lane's first local max)
      unsigned long long m = __ballot(bv == gmax);
      int l = __ffsll((unsigned long long)m) - 1;
      far = __builtin_amdgcn_readlane(bi, l);
    }
    return;
  }

  // ------------------------- gfeat (j-split-2) -------------------------
  const int blk = blockIdx.x - NB;
  const int b  = blk >> 6;
  const int n0 = (blk & 63) * 16;
  const int og = lane & 31;
  const int jg = lane >> 5;
  const int joff = jg * 8;
  const float* fb = features + b * NC * NPTS;
#pragma unroll
  for (int r = 0; r < 4; ++r) {
    int c = r * 64 + lane;
    const float4* s4 = reinterpret_cast<const float4*>(fb + c * NPTS + n0);
    float4 v0 = s4[0], v1 = s4[1], v2 = s4[2], v3 = s4[3];
    float* row = smem + c * RP;
    reinterpret_cast<float4*>(row)[0] = v0;
    reinterpret_cast<float4*>(row)[1] = v1;
    reinterpret_cast<float4*>(row)[2] = v2;
    reinterpret_cast<float4*>(row)[3] = v3;
  }
  float acc[4][8];
#pragma unroll
  for (int k = 0; k < 4; ++k)
#pragma unroll
    for (int nn = 0; nn < 8; ++nn) acc[k][nn] = 0.0f;
#pragma unroll 2
  for (int c = 0; c < NC; ++c) {
    const float4 wq = *reinterpret_cast<const float4*>(w0l + (c * 32 + og) * 4);
    const float* row = smem + c * RP + joff;
    const float4 xa = reinterpret_cast<const float4*>(row)[0];
    const float4 xb4 = reinterpret_cast<const float4*>(row)[1];
    const float wk[4] = {wq.x, wq.y, wq.z, wq.w};
    const float xr[8] = {xa.x, xa.y, xa.z, xa.w, xb4.x, xb4.y, xb4.z, xb4.w};
#pragma unroll
    for (int k = 0; k < 4; ++k)
#pragma unroll
      for (int nn = 0; nn < 8; ++nn)
        acc[k][nn] = fmaf(wk[k], xr[nn], acc[k][nn]);
  }
#pragma unroll
  for (int k = 0; k < 4; ++k) {
    int o = og + 32 * k;
    float* gp = G + ((size_t)(b * NPTS + n0 + joff)) * NH + o;
#pragma unroll
    for (int nn = 0; nn < 8; ++nn) gp[nn * NH] = acc[k][nn];
  }
}

// ---------------------------------------------------------------------------
// Ball query (bit-identical decision math). NO atomics: writes totals only.
// ---------------------------------------------------------------------------
__global__ __launch_bounds__(256) void ball_kernel(
    const float* __restrict__ xyz, const int* __restrict__ inds,
    int* __restrict__ nbr, float* __restrict__ gx, int* __restrict__ totals)
{
  const int wid  = blockIdx.x * 4 + (threadIdx.x >> 6);   // == b*NP + p
  const int lane = threadIdx.x & 63;
  const int b = wid >> 8;
  const float* xb = xyz + b * NPTS * 3;
  const int ci = inds[wid];
  const float cx = xb[ci * 3 + 0], cy = xb[ci * 3 + 1], cz = xb[ci * 3 + 2];
  float nq;
  {
#pragma clang fp contract(off)
    nq = (cx * cx + cy * cy) + cz * cz;
  }
  const float R2 = 0.09f;
  unsigned mask = 0;
  int cntj = 0, firstn = NPTS;
  for (int j = 0; j < 16; ++j) {
#pragma clang fp contract(off)
    int n = lane * 16 + j;   // lane-major: global order == lexicographic
    float x = xb[n * 3 + 0], y = xb[n * 3 + 1], z = xb[n * 3 + 2];
    float nx = (x * x + y * y) + z * z;
    float dt = (cx * x + cy * y) + cz * z;
    float d2 = (nq + nx) - 2.0f * dt;
    if (d2 < R2) { mask |= 1u << j; ++cntj; if (firstn == NPTS) firstn = n; }
  }
  int inc = cntj;
  for (int off = 1; off < 64; off <<= 1) {
    int v = __shfl_up(inc, off);
    if (lane >= off) inc += v;
  }
  int rank  = inc - cntj;
  int total = __shfl(inc, 63);
  for (int j = 0; j < 16; ++j) {
    if (mask & (1u << j)) {
      if (rank < NS) {
        int n = lane * 16 + j;
        nbr[wid * NS + rank] = n;
        float x = xb[n * 3 + 0], y = xb[n * 3 + 1], z = xb[n * 3 + 2];
        gx[wid * 48 + rank * 3 + 0] = (x - cx) / 0.3f;
        gx[wid * 48 + rank * 3 + 1] = (y - cy) / 0.3f;
        gx[wid * 48 + rank * 3 + 2] = (z - cz) / 0.3f;
      }
      ++rank;
    }
  }
  int fmin = firstn;
  for (int off2 = 32; off2 > 0; off2 >>= 1) {
    int ov = __shfl_xor(fmin, off2);
    fmin = min(fmin, ov);
  }
  if (lane < NS && lane >= total) {
    nbr[wid * NS + lane] = fmin;
    float x = xb[fmin * 3 + 0], y = xb[fmin * 3 + 1], z = xb[fmin * 3 + 2];
    gx[wid * 48 + lane * 3 + 0] = (x - cx) / 0.3f;
    gx[wid * 48 + lane * 3 + 1] = (y - cy) / 0.3f;
    gx[wid * 48 + lane * 3 + 2] = (z - cz) / 0.3f;
  }
  if (lane == 0) totals[wid] = total;
}

// ---------------------------------------------------------------------------
// Deterministic bucket build: one block, 1024 threads, 8 tiles each.
// FOUR J-classes: <=2 (pack8), <=4 (pack4), <=8 (pack2), else (pack1).
// Packed-u64 scan (4 class counts x 16 bits). Stable within class.
// ---------------------------------------------------------------------------
__global__ __launch_bounds__(1024) void scan_kernel(
    const int* __restrict__ totals, int* __restrict__ bucket, int* __restrict__ cnt)
{
  __shared__ unsigned long long ssum[16];
  const int t = threadIdx.x;
  int cls[8];
  unsigned long long local = 0;
#pragma unroll
  for (int k = 0; k < 8; ++k) {
    int tot = totals[t * 8 + k];
    int jc = (tot <= 2) ? 0 : (tot <= 4) ? 1 : (tot <= 8) ? 2 : 3;
    cls[k] = jc;
    local += 1ull << (jc * 16);
  }
  unsigned long long inc = local;
  for (int off = 1; off < 64; off <<= 1) {
    unsigned long long v = __shfl_up(inc, off);
    if ((t & 63) >= off) inc += v;
  }
  if ((t & 63) == 63) ssum[t >> 6] = inc;
  __syncthreads();
  if (t == 0) {
    unsigned long long run = 0;
    for (int i = 0; i < 16; ++i) { unsigned long long v = ssum[i]; ssum[i] = run; run += v; }
    cnt[0] = (int)(run & 0xFFFFull);
    cnt[1] = (int)((run >> 16) & 0xFFFFull);
    cnt[2] = (int)((run >> 32) & 0xFFFFull);
    cnt[3] = (int)((run >> 48) & 0xFFFFull);
  }
  __syncthreads();
  unsigned long long excl = (inc - local) + ssum[t >> 6];
  int p0 = (int)(excl & 0xFFFFull);
  int p1 = (int)((excl >> 16) & 0xFFFFull);
  int p2 = (int)((excl >> 32) & 0xFFFFull);
  int p3 = (int)((excl >> 48) & 0xFFFFull);
#pragma unroll
  for (int k = 0; k < 8; ++k) {
    int id = t * 8 + k;
    if (cls[k] == 0)      { bucket[p0] = id; ++p0; }
    else if (cls[k] == 1) { bucket[NT + p1] = id; ++p1; }
    else if (cls[k] == 2) { bucket[2 * NT + p2] = id; ++p2; }
    else                  { bucket[3 * NT + p3] = id; ++p3; }
  }
}

// ---------------------------------------------------------------------------
// 16-slot MLP core (L0 -> L1 -> L2), o2 scheme: lane owns o in {lane,lane+64},
// all 16 slots in registers. acc left raw (pre-BN) for per-tile maxpool.
// ---------------------------------------------------------------------------
__device__ __forceinline__ void mlp16(
    float* __restrict__ xs, const int lane,
    const float* __restrict__ G, const int* __restrict__ idxw,
    const float* __restrict__ gxw,
    const float* __restrict__ w0x, const float* __restrict__ s0v, const float* __restrict__ t0v,
    const float* __restrict__ wl1, const float* __restrict__ s1v, const float* __restrict__ t1v,
    const float* __restrict__ wl2,
    float acc0[16], float acc1[16])
{
  // ---- L0 ----
  {
    const float wa0 = w0x[lane],      wb0 = w0x[128 + lane],      wc0 = w0x[256 + lane];
    const float wa1 = w0x[64 + lane], wb1 = w0x[192 + lane],      wc1 = w0x[320 + lane];
    const float ss0 = s0v[lane], tt0 = t0v[lane];
    const float ss1 = s0v[64 + lane], tt1 = t0v[64 + lane];
    float r0[16], r1[16];
#pragma unroll
    for (int j = 0; j < 16; ++j) {
      int gj = idxw[j];                       // prefolded b*NPTS + nbr
      float gxv = gxw[j * 3 + 0], gyv = gxw[j * 3 + 1], gzv = gxw[j * 3 + 2];
      const float* gp = G + (size_t)gj * NH;
      float g0 = gp[lane], g1 = gp[lane + 64];
      float y0 = fmaf(wa0, gxv, fmaf(wb0, gyv, fmaf(wc0, gzv, g0)));
      float y1 = fmaf(wa1, gxv, fmaf(wb1, gyv, fmaf(wc1, gzv, g1)));
      r0[j] = fmaxf(fmaf(y0, ss0, tt0), 0.0f);
      r1[j] = fmaxf(fmaf(y1, ss1, tt1), 0.0f);
    }
#pragma unroll
    for (int q = 0; q < 4; ++q) {
      *reinterpret_cast<float4*>(xs + lane * RP + q * 4) =
          make_float4(r0[4 * q], r0[4 * q + 1], r0[4 * q + 2], r0[4 * q + 3]);
      *reinterpret_cast<float4*>(xs + (lane + 64) * RP + q * 4) =
          make_float4(r1[4 * q], r1[4 * q + 1], r1[4 * q + 2], r1[4 * q + 3]);
    }
  }

  // ---- L1 ----
#pragma unroll
  for (int j = 0; j < 16; ++j) { acc0[j] = 0.0f; acc1[j] = 0.0f; }
#pragma unroll 2
  for (int c = 0; c < NH; ++c) {
    const float2 wv = *reinterpret_cast<const float2*>(wl1 + (c * 64 + lane) * 2);
#pragma unroll
    for (int q = 0; q < 4; ++q) {
      const float4 xq = *reinterpret_cast<const float4*>(xs + c * RP + q * 4);
      acc0[4 * q + 0] = fmaf(wv.x, xq.x, acc0[4 * q + 0]);
      acc1[4 * q + 0] = fmaf(wv.y, xq.x, acc1[4 * q + 0]);
      acc0[4 * q + 1] = fmaf(wv.x, xq.y, acc0[4 * q + 1]);
      acc1[4 * q + 1] = fmaf(wv.y, xq.y, acc1[4 * q + 1]);
      acc0[4 * q + 2] = fmaf(wv.x, xq.z, acc0[4 * q + 2]);
      acc1[4 * q + 2] = fmaf(wv.y, xq.z, acc1[4 * q + 2]);
      acc0[4 * q + 3] = fmaf(wv.x, xq.w, acc0[4 * q + 3]);
      acc1[4 * q + 3] = fmaf(wv.y, xq.w, acc1[4 * q + 3]);
    }
  }
  // BN+ReLU, write x2 (in-wave LDS ordering: own-plane reads precede writes)
  {
    const float ssa = s1v[lane], tta = t1v[lane];
    const float ssb = s1v[64 + lane], ttb = t1v[64 + lane];
#pragma unroll
    for (int q = 0; q < 4; ++q) {
      float4 ra, rb;
      ra.x = fmaxf(fmaf(acc0[4 * q + 0], ssa, tta), 0.0f);
      ra.y = fmaxf(fmaf(acc0[4 * q + 1], ssa, tta), 0.0f);
      ra.z = fmaxf(fmaf(acc0[4 * q + 2], ssa, tta), 0.0f);
      ra.w = fmaxf(fmaf(acc0[4 * q + 3], ssa, tta), 0.0f);
      rb.x = fmaxf(fmaf(acc1[4 * q + 0], ssb, ttb), 0.0f);
      rb.y = fmaxf(fmaf(acc1[4 * q + 1], ssb, ttb), 0.0f);
      rb.z = fmaxf(fmaf(acc1[4 * q + 2], ssb, ttb), 0.0f);
      rb.w = fmaxf(fmaf(acc1[4 * q + 3], ssb, ttb), 0.0f);
      *reinterpret_cast<float4*>(xs + lane * RP + q * 4) = ra;
      *reinterpret_cast<float4*>(xs + (lane + 64) * RP + q * 4) = rb;
    }
  }

  // ---- L2 (raw acc; BN+maxpool done by caller per tile) ----
#pragma unroll
  for (int j = 0; j < 16; ++j) { acc0[j] = 0.0f; acc1[j] = 0.0f; }
#pragma unroll 2
  for (int c = 0; c < NH; ++c) {
    const float2 wv = *reinterpret_cast<const float2*>(wl2 + (c * 64 + lane) * 2);
#pragma unroll
    for (int q = 0; q < 4; ++q) {
      const float4 xq = *reinterpret_cast<const float4*>(xs + c * RP + q * 4);
      acc0[4 * q + 0] = fmaf(wv.x, xq.x, acc0[4 * q + 0]);
      acc1[4 * q + 0] = fmaf(wv.y, xq.x, acc1[4 * q + 0]);
      acc0[4 * q + 1] = fmaf(wv.x, xq.y, acc0[4 * q + 1]);
      acc1[4 * q + 1] = fmaf(wv.y, xq.y, acc1[4 * q + 1]);
      acc0[4 * q + 2] = fmaf(wv.x, xq.z, acc0[4 * q + 2]);
      acc1[4 * q + 2] = fmaf(wv.y, xq.z, acc1[4 * q + 2]);
      acc0[4 * q + 3] = fmaf(wv.x, xq.w, acc0[4 * q + 3]);
      acc1[4 * q + 3] = fmaf(wv.y, xq.w, acc1[4 * q + 3]);
    }
  }
}

// ---------------------------------------------------------------------------
// Epilogue for TPW tiles (16/TPW slots each): maxpool per tile -> FC1/2/3.
// Tile ids come from LDS (tl[k], compile-time k). f at xs[k*128..],
// h at xs[TPW*128 + k*128..]. TPW=8 uses exactly the 2048-float plane.
// ---------------------------------------------------------------------------
template <int TPW>
__device__ __forceinline__ void fc_epilogue(
    float* __restrict__ xs, const int lane, const int* __restrict__ tl,
    float acc0[16], float acc1[16],
    const float* __restrict__ s2v, const float* __restrict__ t2v,
    const float* __restrict__ fl1, const float* __restrict__ fs1, const float* __restrict__ ft1,
    const float* __restrict__ fl2, const float* __restrict__ fs2, const float* __restrict__ ft2,
    const float* __restrict__ fl3, const float* __restrict__ b3, float* __restrict__ out)
{
  constexpr int SPT = 16 / TPW;
  // ---- per-tile BN+ReLU+maxpool -> f vectors ----
  {
    const float ssa = s2v[lane], tta = t2v[lane];
    const float ssb = s2v[64 + lane], ttb = t2v[64 + lane];
#pragma unroll
    for (int k = 0; k < TPW; ++k) {
      float fo0 = 0.0f, fo1 = 0.0f;
#pragma unroll
      for (int r = 0; r < SPT; ++r) {
        fo0 = fmaxf(fo0, fmaxf(fmaf(acc0[k * SPT + r], ssa, tta), 0.0f));
        fo1 = fmaxf(fo1, fmaxf(fmaf(acc1[k * SPT + r], ssb, ttb), 0.0f));
      }
      xs[k * 128 + lane] = fo0;
      xs[k * 128 + 64 + lane] = fo1;
    }
  }
  constexpr int HB = TPW * 128;

  float h0[TPW], h1[TPW];

  // ---- FC1 ----
#pragma unroll
  for (int k = 0; k < TPW; ++k) { h0[k] = 0.0f; h1[k] = 0.0f; }
#pragma unroll 4
  for (int c4 = 0; c4 < 32; ++c4) {
    float4 fq[TPW];
#pragma unroll
    for (int k = 0; k < TPW; ++k)
      fq[k] = *reinterpret_cast<const float4*>(xs + k * 128 + c4 * 4);
#pragma unroll
    for (int cc = 0; cc < 4; ++cc) {
      const float2 wv = *reinterpret_cast<const float2*>(fl1 + ((c4 * 4 + cc) * 64 + lane) * 2);
#pragma unroll
      for (int k = 0; k < TPW; ++k) {
        float fv = (cc == 0) ? fq[k].x : (cc == 1) ? fq[k].y : (cc == 2) ? fq[k].z : fq[k].w;
        h0[k] = fmaf(wv.x, fv, h0[k]);
        h1[k] = fmaf(wv.y, fv, h1[k]);
      }
    }
  }
#pragma unroll
  for (int k = 0; k < TPW; ++k) {
    xs[HB + k * 128 + lane]      = fmaxf(fmaf(h0[k], fs1[lane],      ft1[lane]),      0.0f);
    xs[HB + k * 128 + 64 + lane] = fmaxf(fmaf(h1[k], fs1[lane + 64], ft1[lane + 64]), 0.0f);
  }

  // ---- FC2 ----
#pragma unroll
  for (int k = 0; k < TPW; ++k) { h0[k] = 0.0f; h1[k] = 0.0f; }
#pragma unroll 4
  for (int c4 = 0; c4 < 32; ++c4) {
    float4 fq[TPW];
#pragma unroll
    for (int k = 0; k < TPW; ++k)
      fq[k] = *reinterpret_cast<const float4*>(xs + HB + k * 128 + c4 * 4);
#pragma unroll
    for (int cc = 0; cc < 4; ++cc) {
      const float2 wv = *reinterpret_cast<const float2*>(fl2 + ((c4 * 4 + cc) * 64 + lane) * 2);
#pragma unroll
      for (int k = 0; k < TPW; ++k) {
        float fv = (cc == 0) ? fq[k].x : (cc == 1) ? fq[k].y : (cc == 2) ? fq[k].z : fq[k].w;
        h0[k] = fmaf(wv.x, fv, h0[k]);
        h1[k] = fmaf(wv.y, fv, h1[k]);
      }
    }
  }
#pragma unroll
  for (int k = 0; k < TPW; ++k) {
    xs[k * 128 + lane]      = fmaxf(fmaf(h0[k], fs2[lane],      ft2[lane]),      0.0f);
    xs[k * 128 + 64 + lane] = fmaxf(fmaf(h1[k], fs2[lane + 64], ft2[lane + 64]), 0.0f);
  }

  // ---- FC3 ----
#pragma unroll
  for (int k = 0; k < TPW; ++k) { h0[k] = 0.0f; h1[k] = 0.0f; }
#pragma unroll 4
  for (int c4 = 0; c4 < 32; ++c4) {
    float4 fq[TPW];
#pragma unroll
    for (int k = 0; k < TPW; ++k)
      fq[k] = *reinterpret_cast<const float4*>(xs + k * 128 + c4 * 4);
#pragma unroll
    for (int cc = 0; cc < 4; ++cc) {
      const float2 wv = *reinterpret_cast<const float2*>(fl3 + ((c4 * 4 + cc) * 64 + lane) * 2);
#pragma unroll
      for (int k = 0; k < TPW; ++k) {
        float fv = (cc == 0) ? fq[k].x : (cc == 1) ? fq[k].y : (cc == 2) ? fq[k].z : fq[k].w;
        h0[k] = fmaf(wv.x, fv, h0[k]);
        h1[k] = fmaf(wv.y, fv, h1[k]);
      }
    }
  }
#pragma unroll
  for (int k = 0; k < TPW; ++k) {
    int tk = tl[k];                         // LDS read, compile-time k
    int b = tk >> 8, p = tk & 255;
    out[(b * NOUT + lane) * NP + p] = h0[k] + b3[lane];   // lane < 97 always
    if (lane < NOUT - 64)
      out[(b * NOUT + lane + 64) * NP + p] = h1[k] + b3[lane + 64];
  }
}

// ---------------------------------------------------------------------------
// Main kernel: 512-thread blocks = 8 independent waves (no barriers). Each
// wave carries a 16-slot task: 8xJ2, 4xJ4, 2xJ8, or 1xJ16 tiles via the
// class buckets. Tile ids routed through LDS (rule #20).
// ---------------------------------------------------------------------------
__global__ __launch_bounds__(512) void main_kernel(
    const int* __restrict__ nbr, const float* __restrict__ gx,
    const int* __restrict__ bucket, const int* __restrict__ cnt,
    const float* __restrict__ G,
    const float* __restrict__ w0x, const float* __restrict__ s0v, const float* __restrict__ t0v,
    const float* __restrict__ wl1, const float* __restrict__ s1v, const float* __restrict__ t1v,
    const float* __restrict__ wl2, const float* __restrict__ s2v, const float* __restrict__ t2v,
    const float* __restrict__ fl1, const float* __restrict__ fs1, const float* __restrict__ ft1,
    const float* __restrict__ fl2, const float* __restrict__ fs2, const float* __restrict__ ft2,
    const float* __restrict__ fl3, const float* __restrict__ b3, float* __restrict__ out)
{
  __shared__ __align__(16) float xt[8][NH * RP];   // 64 KB (8 waves)
  __shared__ float gxs[8][NS][3];
  __shared__ int   idxs[8][NS];
  __shared__ int   sh_t[8][8];

  const int w    = threadIdx.x >> 6;              // 0..7
  const int lane = threadIdx.x & 63;
  const int g    = blockIdx.x * 8 + w;

  const int c0 = cnt[0], c1 = cnt[1], c2 = cnt[2], c3 = cnt[3];
  const int n8 = (c0 + 7) >> 3;
  const int n4 = (c1 + 3) >> 2;
  const int n2 = (c2 + 1) >> 1;
  if (g >= n8 + n4 + n2 + c3) return;             // no barriers: early exit ok

  // wave-uniform pack class; each lane loads its own tile id (no reg arrays)
  int tpw, myt;
  if (g < n8) {
    tpw = 8;
    myt = bucket[min(8 * g + (lane & 7), c0 - 1)];
  } else if (g < n8 + n4) {
    tpw = 4;
    myt = bucket[NT + min(4 * (g - n8) + (lane & 3), c1 - 1)];
  } else if (g < n8 + n4 + n2) {
    tpw = 2;
    myt = bucket[2 * NT + min(2 * (g - n8 - n4) + (lane & 1), c2 - 1)];
  } else {
    tpw = 1;
    myt = bucket[3 * NT + (g - n8 - n4 - n2)];
  }
  if (lane < 8) sh_t[w][lane] = myt;

  float* xs = &xt[w][0];

  // ---- prologue: gather 16 (tile, slot) pairs into LDS ----
  if (lane < 16) {
    int ti, r;
    if (tpw == 8)      { ti = lane >> 1; r = lane & 1; }
    else if (tpw == 4) { ti = lane >> 2; r = lane & 3; }
    else if (tpw == 2) { ti = lane >> 3; r = lane & 7; }
    else               { ti = 0;         r = lane; }
    int tk = sh_t[w][ti];                 // LDS-indexed read (in-wave ordered)
    int bk = tk >> 8;
    idxs[w][lane] = bk * NPTS + nbr[tk * NS + r];
    gxs[w][lane][0] = gx[tk * 48 + r * 3 + 0];
    gxs[w][lane][1] = gx[tk * 48 + r * 3 + 1];
    gxs[w][lane][2] = gx[tk * 48 + r * 3 + 2];
  }
  // single wave owns its LDS plane: in-wave lgkmcnt orders write->read

  float acc0[16], acc1[16];
  mlp16(xs, lane, G, idxs[w], &gxs[w][0][0],
        w0x, s0v, t0v, wl1, s1v, t1v, wl2, acc0, acc1);

  if (tpw == 8) {
    fc_epilogue<8>(xs, lane, sh_t[w], acc0, acc1, s2v, t2v,
                   fl1, fs1, ft1, fl2, fs2, ft2, fl3, b3, out);
  } else if (tpw == 4) {
    fc_epilogue<4>(xs, lane, sh_t[w], acc0, acc1, s2v, t2v,
                   fl1, fs1, ft1, fl2, fs2, ft2, fl3, b3, out);
  } else if (tpw == 2) {
    fc_epilogue<2>(xs, lane, sh_t[w], acc0, acc1, s2v, t2v,
                   fl1, fs1, ft1, fl2, fs2, ft2, fl3, b3, out);
  } else {
    fc_epilogue<1>(xs, lane, sh_t[w], acc0, acc1, s2v, t2v,
                   fl1, fs1, ft1, fl2, fs2, ft2, fl3, b3, out);
  }
}

extern "C" void kernel_launch(void* const* d_in, const int* in_sizes, int n_in,
                              void* d_out, int out_size, void* d_ws, size_t ws_size,
                              hipStream_t stream) {
  const float* xyz      = (const float*)d_in[0];
  const float* features = (const float*)d_in[1];
  const float* sa_w0 = (const float*)d_in[2];
  const float* sa_s0 = (const float*)d_in[3];
  const float* sa_t0 = (const float*)d_in[4];
  const float* sa_w1 = (const float*)d_in[5];
  const float* sa_s1 = (const float*)d_in[6];
  const float* sa_t1 = (const float*)d_in[7];
  const float* sa_w2 = (const float*)d_in[8];
  const float* sa_s2 = (const float*)d_in[9];
  const float* sa_t2 = (const float*)d_in[10];
  const float* fc_w1 = (const float*)d_in[11];
  const float* fc_s1 = (const float*)d_in[12];
  const float* fc_t1 = (const float*)d_in[13];
  const float* fc_w2 = (const float*)d_in[14];
  const float* fc_s2 = (const float*)d_in[15];
  const float* fc_t2 = (const float*)d_in[16];
  const float* fc_w3 = (const float*)d_in[17];
  const float* fc_b3 = (const float*)d_in[18];
  float* out = (float*)d_out;

  char* ws = (char*)d_ws;
  int* inds = (int*)ws;            ws += (size_t)NT * sizeof(int);
  float* w0l  = (float*)ws;        ws += (size_t)256 * 128 * sizeof(float);
  float* w0x  = (float*)ws;        ws += (size_t)3 * 128 * sizeof(float);
  float* wl1  = (float*)ws;        ws += (size_t)128 * 128 * sizeof(float);
  float* wl2  = (float*)ws;        ws += (size_t)128 * 128 * sizeof(float);
  float* fl1  = (float*)ws;        ws += (size_t)128 * 128 * sizeof(float);
  float* fl2  = (float*)ws;        ws += (size_t)128 * 128 * sizeof(float);
  float* fl3  = (float*)ws;        ws += (size_t)128 * 128 * sizeof(float);
  float* G    = (float*)ws;        ws += (size_t)NB * NPTS * NH * sizeof(float);
  int*   nbr  = (int*)ws;          ws += (size_t)NT * NS * sizeof(int);
  float* gx   = (float*)ws;        ws += (size_t)NT * 48 * sizeof(float);
  int* totals = (int*)ws;          ws += (size_t)NT * sizeof(int);
  int* bucket = (int*)ws;          ws += (size_t)4 * NT * sizeof(int);
  int* cnt    = (int*)ws;          ws += 16 * sizeof(int);

  prep_kernel<<<128, 256, 0, stream>>>(sa_w0, sa_w1, sa_w2, fc_w1, fc_w2, fc_w3,
                                       w0l, w0x, wl1, wl2, fl1, fl2, fl3);
  fused_fps_gfeat_kernel<<<NB + NGF, 64, 0, stream>>>(
      xyz, inds, features, w0l, G);
  ball_kernel<<<NT / 4, 256, 0, stream>>>(xyz, inds, nbr, gx, totals);
  scan_kernel<<<1, 1024, 0, stream>>>(totals, bucket, cnt);
  main_kernel<<<NT / 8, 512, 0, stream>>>(
      nbr, gx, bucket, cnt, G,
      w0x, sa_s0, sa_t0,
      wl1, sa_s1, sa_t1,
      wl2, sa_s2, sa_t2,
      fl1, fc_s1, fc_t1,
      fl2, fc_s2, fc_t2,
      fl3, fc_b3, out);
}